// Round 4
// baseline (603.770 us; speedup 1.0000x reference)
//
#include <hip/hip_runtime.h>
#include <stdint.h>

#define OUT_F 4096
#define IN_F  4096
#define MROWS 8192   // 4*2048

typedef __attribute__((ext_vector_type(8))) short  shortx8;   // 8 bf16 = 4 VGPRs
typedef __attribute__((ext_vector_type(4))) float  floatx4;
typedef __attribute__((ext_vector_type(4))) int    intx4;

// fp32 -> bf16 bits, round-to-nearest-even
__device__ __forceinline__ unsigned short f32_to_bf16(float f) {
    unsigned int u = __builtin_bit_cast(unsigned int, f);
    u += 0x7FFFu + ((u >> 16) & 1u);
    return (unsigned short)(u >> 16);
}

// async global->LDS, 16B per lane. LDS dest = wave-uniform base + lane*16.
__device__ __forceinline__ void gload_lds16(const void* gsrc, void* ldst) {
    __builtin_amdgcn_global_load_lds(
        (const __attribute__((address_space(1))) uint32_t*)gsrc,
        (__attribute__((address_space(3))) uint32_t*)ldst,
        16, 0, 0);
}

// ---------------- fused preprocessing: x fp32->bf16  +  dequant W ----------------
// Streaming, zero-reuse data: nontemporal loads/stores keep L2/L3 clean.
#define CAST_BLOCKS 16384
__global__ void __launch_bounds__(256)
preprocess_kernel(const float* __restrict__ x, short* __restrict__ xb,
                  const int* __restrict__ q, const float* __restrict__ s,
                  short* __restrict__ wb) {
    const int b = blockIdx.x;
    if (b < CAST_BLOCKS) {
        int64_t i = ((int64_t)b * 256 + threadIdx.x) * 8;
        floatx4 v0 = __builtin_nontemporal_load((const floatx4*)(x + i));
        floatx4 v1 = __builtin_nontemporal_load((const floatx4*)(x + i + 4));
        shortx8 o;
        o[0] = (short)f32_to_bf16(v0[0]); o[1] = (short)f32_to_bf16(v0[1]);
        o[2] = (short)f32_to_bf16(v0[2]); o[3] = (short)f32_to_bf16(v0[3]);
        o[4] = (short)f32_to_bf16(v1[0]); o[5] = (short)f32_to_bf16(v1[1]);
        o[6] = (short)f32_to_bf16(v1[2]); o[7] = (short)f32_to_bf16(v1[3]);
        __builtin_nontemporal_store(o, (shortx8*)(xb + i));
    } else {
        int64_t i = ((int64_t)(b - CAST_BLOCKS) * 256 + threadIdx.x) * 8;
        float sc = s[i >> 6];              // 8 elems always within one 64-block
        intx4 a = __builtin_nontemporal_load((const intx4*)(q + i));
        intx4 c = __builtin_nontemporal_load((const intx4*)(q + i + 4));
        shortx8 o;
        o[0] = (short)f32_to_bf16((float)a[0] * sc); o[1] = (short)f32_to_bf16((float)a[1] * sc);
        o[2] = (short)f32_to_bf16((float)a[2] * sc); o[3] = (short)f32_to_bf16((float)a[3] * sc);
        o[4] = (short)f32_to_bf16((float)c[0] * sc); o[5] = (short)f32_to_bf16((float)c[1] * sc);
        o[6] = (short)f32_to_bf16((float)c[2] * sc); o[7] = (short)f32_to_bf16((float)c[3] * sc);
        __builtin_nontemporal_store(o, (shortx8*)(wb + i));
    }
}

// ---------------- bf16 GEMM  C[M,N] = A[M,K] * B[N,K]^T + bias ----------------
// BK=64 variant of the m97 structure: 128x128 tile, 64 K-iterations (half the
// barrier drains of BK=32), 32 MFMAs per barrier pair per wave.
// LDS row = 64 shorts = 128 B = exactly 32 banks, so chunk (row, kblk) is
// stored XOR-swizzled at pos = kblk ^ (row&7): a 16-lane b128 phase covers all
// 32 banks exactly 2x (2-way = free, m136). Write side satisfies the
// global_load_lds base+lane*16 constraint: lane -> (row = seg*8 + lane>>3,
// pos = lane&7), so it must fetch global chunk (lane&7) ^ (lane>>3)
// (seg-invariant because segments are 8-row aligned).
__global__ void __launch_bounds__(256)
gemm_bf16_kernel(const short* __restrict__ A, const short* __restrict__ B,
                 const float* __restrict__ bias, float* __restrict__ C) {
    __shared__ short sA[128 * 64];   // 16 KB
    __shared__ short sB[128 * 64];   // 16 KB

    const int tid  = threadIdx.x;
    const int wave = tid >> 6;       // 0..3
    const int lane = tid & 63;
    const int wr   = wave >> 1;      // 0..1
    const int wc   = wave & 1;       // 0..1

    const int row0 = blockIdx.y * 128;   // M offset
    const int col0 = blockIdx.x * 128;   // N offset

    // staging: wave w covers rows [w*32, w*32+32) as 4 segments of 8 rows.
    const int lr = lane >> 3;                      // 0..7 row within segment
    const int lc = ((lane & 7) ^ lr) * 8;          // swizzled global chunk (shorts)
    const short* gA = A + (int64_t)(row0 + wave * 32 + lr) * IN_F + lc;
    const short* gB = B + (int64_t)(col0 + wave * 32 + lr) * IN_F + lc;
    short* lA = sA + wave * 2048;    // wave base; segment s at +s*512 shorts
    short* lB = sB + wave * 2048;

    floatx4 acc[4][4];
#pragma unroll
    for (int i = 0; i < 4; i++)
#pragma unroll
        for (int j = 0; j < 4; j++) acc[i][j] = (floatx4)(0.0f);

    const int m_lane = lane & 15;          // A: m index / B: n index
    const int quad   = lane >> 4;          // 0..3
    const int m7     = m_lane & 7;
    // fragment (mt, kk): k-chunk kblk = kk*4 + quad, read at pos = kblk ^ (row&7)
    const int kpos0 = ((quad)     ^ m7) * 8;   // kk = 0
    const int kpos1 = ((4 + quad) ^ m7) * 8;   // kk = 1

    for (int k0 = 0; k0 < IN_F; k0 += 64) {
#pragma unroll
        for (int s2 = 0; s2 < 4; s2++) {
            gload_lds16(gA + s2 * 8 * IN_F, lA + s2 * 512);
            gload_lds16(gB + s2 * 8 * IN_F, lB + s2 * 512);
        }
        gA += 64; gB += 64;
        __syncthreads();   // drains vmcnt(0): LDS tiles complete

#pragma unroll
        for (int kk = 0; kk < 2; kk++) {
            const int kp = kk ? kpos1 : kpos0;
            shortx8 bfr[4];
#pragma unroll
            for (int nt = 0; nt < 4; nt++)
                bfr[nt] = *(const shortx8*)&sB[(wc * 64 + nt * 16 + m_lane) * 64 + kp];
#pragma unroll
            for (int mt = 0; mt < 4; mt++) {
                shortx8 af = *(const shortx8*)&sA[(wr * 64 + mt * 16 + m_lane) * 64 + kp];
#pragma unroll
                for (int nt = 0; nt < 4; nt++)
                    acc[mt][nt] = __builtin_amdgcn_mfma_f32_16x16x32_bf16(
                        af, bfr[nt], acc[mt][nt], 0, 0, 0);
            }
        }
        __syncthreads();   // all waves done reading before next overwrite
    }

    // epilogue: C/D layout col = lane&15, row = (lane>>4)*4 + reg  [m89/m91]
    const int out_r_base = row0 + wr * 64;
    const int out_c_base = col0 + wc * 64;
#pragma unroll
    for (int nt = 0; nt < 4; nt++) {
        const int gcol = out_c_base + nt * 16 + m_lane;
        const float bv = bias[gcol];
#pragma unroll
        for (int mt = 0; mt < 4; mt++) {
            const int grow = out_r_base + mt * 16 + quad * 4;
            float* outp = C + (int64_t)grow * OUT_F + gcol;
#pragma unroll
            for (int r = 0; r < 4; r++)
                outp[(int64_t)r * OUT_F] = acc[mt][nt][r] + bv;
        }
    }
}

extern "C" void kernel_launch(void* const* d_in, const int* in_sizes, int n_in,
                              void* d_out, int out_size, void* d_ws, size_t ws_size,
                              hipStream_t stream) {
    const float* x    = (const float*)d_in[0];
    const int*   qw   = (const int*)d_in[1];
    const float* sc   = (const float*)d_in[2];
    const float* bias = (const float*)d_in[3];
    float*       out  = (float*)d_out;

    // workspace: [x_bf16: 64 MiB][w_bf16: 32 MiB]
    short* xb = (short*)d_ws;
    short* wb = (short*)((char*)d_ws + (size_t)MROWS * IN_F * sizeof(short));

    preprocess_kernel<<<CAST_BLOCKS + (OUT_F * IN_F) / 8 / 256, 256, 0, stream>>>(
        x, xb, qw, sc, wb);

    dim3 grid(OUT_F / 128, MROWS / 128);   // (32, 64) = 2048 blocks
    gemm_bf16_kernel<<<grid, 256, 0, stream>>>(xb, wb, bias, out);
}

// Round 5
// 572.883 us; speedup vs baseline: 1.0539x; 1.0539x over previous
//
#include <hip/hip_runtime.h>
#include <stdint.h>

#define OUT_F 4096
#define IN_F  4096
#define MROWS 8192   // 4*2048

typedef __attribute__((ext_vector_type(8))) short  shortx8;   // 8 bf16 = 4 VGPRs
typedef __attribute__((ext_vector_type(4))) float  floatx4;
typedef __attribute__((ext_vector_type(4))) int    intx4;

// fp32 -> bf16 bits, round-to-nearest-even
__device__ __forceinline__ unsigned short f32_to_bf16(float f) {
    unsigned int u = __builtin_bit_cast(unsigned int, f);
    u += 0x7FFFu + ((u >> 16) & 1u);
    return (unsigned short)(u >> 16);
}

// async global->LDS, 16B per lane. LDS dest = wave-uniform base + lane*16.
__device__ __forceinline__ void gload_lds16(const void* gsrc, void* ldst) {
    __builtin_amdgcn_global_load_lds(
        (const __attribute__((address_space(1))) uint32_t*)gsrc,
        (__attribute__((address_space(3))) uint32_t*)ldst,
        16, 0, 0);
}

// ---------------- preprocessing: grid-stride persistent blocks ----------------
// R1-R4 used 24576 one-shot blocks (one 32B load pair + 16B store per thread,
// then exit) -> ~1.4 TB/s effective. Persistent 2048-block grid-stride keeps
// ~8 blocks/CU resident with ~12 independent iterations/thread of in-flight
// loads -> deep MLP, one launch ramp.
#define PRE_BLOCKS   2048
#define CAST_CHUNKS  ((MROWS * IN_F) / 8)   // 4194304 chunks of 8 fp32 -> bf16
#define DEQ_CHUNKS   ((OUT_F * IN_F) / 8)   // 2097152 chunks of 8 int32 -> bf16
__global__ void __launch_bounds__(256)
preprocess_kernel(const float* __restrict__ x, short* __restrict__ xb,
                  const int* __restrict__ q, const float* __restrict__ s,
                  short* __restrict__ wb) {
    const int gstride = PRE_BLOCKS * 256;
    const int gtid = blockIdx.x * 256 + threadIdx.x;
    // chunks are contiguous per iteration; all 256 threads of a block take the
    // same branch except at the single domain boundary.
    for (int c = gtid; c < CAST_CHUNKS + DEQ_CHUNKS; c += gstride) {
        if (c < CAST_CHUNKS) {
            int64_t i = (int64_t)c * 8;
            float4 v0 = *(const float4*)(x + i);
            float4 v1 = *(const float4*)(x + i + 4);
            shortx8 o;
            o[0] = (short)f32_to_bf16(v0.x); o[1] = (short)f32_to_bf16(v0.y);
            o[2] = (short)f32_to_bf16(v0.z); o[3] = (short)f32_to_bf16(v0.w);
            o[4] = (short)f32_to_bf16(v1.x); o[5] = (short)f32_to_bf16(v1.y);
            o[6] = (short)f32_to_bf16(v1.z); o[7] = (short)f32_to_bf16(v1.w);
            *(shortx8*)(xb + i) = o;
        } else {
            int64_t i = (int64_t)(c - CAST_CHUNKS) * 8;
            float sc = s[i >> 6];              // 8 elems always within one 64-block
            intx4 a  = *(const intx4*)(q + i);
            intx4 b2 = *(const intx4*)(q + i + 4);
            shortx8 o;
            o[0] = (short)f32_to_bf16((float)a[0]  * sc); o[1] = (short)f32_to_bf16((float)a[1]  * sc);
            o[2] = (short)f32_to_bf16((float)a[2]  * sc); o[3] = (short)f32_to_bf16((float)a[3]  * sc);
            o[4] = (short)f32_to_bf16((float)b2[0] * sc); o[5] = (short)f32_to_bf16((float)b2[1] * sc);
            o[6] = (short)f32_to_bf16((float)b2[2] * sc); o[7] = (short)f32_to_bf16((float)b2[3] * sc);
            *(shortx8*)(wb + i) = o;
        }
    }
}

// ---------------- bf16 GEMM  C[M,N] = A[M,K] * B[N,K]^T + bias ----------------
// R2-exact (345 us, MfmaUtil 36%, conflicts 0): m97 structure, 128x128 tile,
// BK=32, XOR bank swizzle, global_load_lds width=16, 2-barrier K-loop.
__global__ void __launch_bounds__(256)
gemm_bf16_kernel(const short* __restrict__ A, const short* __restrict__ B,
                 const float* __restrict__ bias, float* __restrict__ C) {
    __shared__ short sA[128 * 32];   // 8 KB, row stride 32 shorts (64 B)
    __shared__ short sB[128 * 32];   // 8 KB

    const int tid  = threadIdx.x;
    const int wave = tid >> 6;       // 0..3
    const int lane = tid & 63;
    const int wr   = wave >> 1;      // 0..1
    const int wc   = wave & 1;       // 0..1

    const int row0 = blockIdx.y * 128;   // M offset
    const int col0 = blockIdx.x * 128;   // N offset

    // staging: lane's LDS slot (row = lane>>2, pos = lane&3) holds global chunk
    // kblk = pos ^ ((row>>1)&3)  (seg-base invariant: segments 16-row aligned)
    const int lr = lane >> 2;
    const int lc = ((lane & 3) ^ ((lr >> 1) & 3)) * 8;
    const short* gA = A + (int64_t)(row0 + wave * 32 + lr) * IN_F + lc;
    const short* gB = B + (int64_t)(col0 + wave * 32 + lr) * IN_F + lc;
    short* lA = sA + wave * 1024;    // wave-uniform LDS base; +512 for 2nd 16-row seg
    short* lB = sB + wave * 1024;

    floatx4 acc[4][4];
#pragma unroll
    for (int i = 0; i < 4; i++)
#pragma unroll
        for (int j = 0; j < 4; j++) acc[i][j] = (floatx4)(0.0f);

    const int m_lane = lane & 15;          // A: m index / B: n index
    // read-side swizzle: row = 16*t + m_lane, so (row>>1)&3 = (m_lane>>1)&3
    const int kpos = ((lane >> 4) ^ ((m_lane >> 1) & 3)) * 8;

    for (int k0 = 0; k0 < IN_F; k0 += 32) {
        gload_lds16(gA,              lA);
        gload_lds16(gA + 16 * IN_F,  lA + 512);
        gload_lds16(gB,              lB);
        gload_lds16(gB + 16 * IN_F,  lB + 512);
        gA += 32; gB += 32;
        __syncthreads();   // drains vmcnt(0): LDS tiles complete

        shortx8 af[4], bfr[4];
#pragma unroll
        for (int mt = 0; mt < 4; mt++)
            af[mt] = *(const shortx8*)&sA[(wr * 64 + mt * 16 + m_lane) * 32 + kpos];
#pragma unroll
        for (int nt = 0; nt < 4; nt++)
            bfr[nt] = *(const shortx8*)&sB[(wc * 64 + nt * 16 + m_lane) * 32 + kpos];
#pragma unroll
        for (int mt = 0; mt < 4; mt++)
#pragma unroll
            for (int nt = 0; nt < 4; nt++)
                acc[mt][nt] = __builtin_amdgcn_mfma_f32_16x16x32_bf16(
                    af[mt], bfr[nt], acc[mt][nt], 0, 0, 0);
        __syncthreads();   // all waves done reading before next overwrite
    }

    // epilogue: C/D layout col = lane&15, row = (lane>>4)*4 + reg  [m89/m91]
    const int quad = lane >> 4;
    const int out_r_base = row0 + wr * 64;
    const int out_c_base = col0 + wc * 64;
#pragma unroll
    for (int nt = 0; nt < 4; nt++) {
        const int gcol = out_c_base + nt * 16 + m_lane;
        const float bv = bias[gcol];
#pragma unroll
        for (int mt = 0; mt < 4; mt++) {
            const int grow = out_r_base + mt * 16 + quad * 4;
            float* outp = C + (int64_t)grow * OUT_F + gcol;
#pragma unroll
            for (int r = 0; r < 4; r++)
                outp[(int64_t)r * OUT_F] = acc[mt][nt][r] + bv;
        }
    }
}

extern "C" void kernel_launch(void* const* d_in, const int* in_sizes, int n_in,
                              void* d_out, int out_size, void* d_ws, size_t ws_size,
                              hipStream_t stream) {
    const float* x    = (const float*)d_in[0];
    const int*   qw   = (const int*)d_in[1];
    const float* sc   = (const float*)d_in[2];
    const float* bias = (const float*)d_in[3];
    float*       out  = (float*)d_out;

    // workspace: [x_bf16: 64 MiB][w_bf16: 32 MiB]
    short* xb = (short*)d_ws;
    short* wb = (short*)((char*)d_ws + (size_t)MROWS * IN_F * sizeof(short));

    preprocess_kernel<<<PRE_BLOCKS, 256, 0, stream>>>(x, xb, qw, sc, wb);

    dim3 grid(OUT_F / 128, MROWS / 128);   // (32, 64) = 2048 blocks
    gemm_bf16_kernel<<<grid, 256, 0, stream>>>(xb, wb, bias, out);
}